// Round 8
// baseline (134.918 us; speedup 1.0000x reference)
//
#include <hip/hip_runtime.h>
#include <hip/hip_bf16.h>

// Problem: out[b,l,:] = code[b,l,:] @ W[l]   (B=256, L=64, C=256, HW=1024, fp32)
#define B_  256
#define L_  64
#define C_  256
#define HW_ 1024

typedef float  floatx4 __attribute__((ext_vector_type(4)));
typedef __bf16 bf16x8  __attribute__((ext_vector_type(8)));
typedef __bf16 bf16x4  __attribute__((ext_vector_type(4)));
typedef __bf16 bf16x2  __attribute__((ext_vector_type(2)));

#define LDA_ROW 80   // A row stride BYTES (32 k bf16 + pad; write ~2-way, read free -- R7-verified)
#define LDB_ROW 64   // B row stride BYTES (32 bf16; chunk-XOR swizzle g2x)

// Barrier that does NOT drain outstanding global loads (vmcnt): only LDS ops
// must be visible across the barrier; register prefetch stays in flight.
#define BARRIER_LDS() asm volatile("s_waitcnt lgkmcnt(0)\n\ts_barrier" ::: "memory")

// ROUND 8: R7 + two priced fixes (byte count unchanged -- 134 MB is this
// lattice's floor and forces 1 block/CU, so the lever is per-CU pipe duty):
// (1) B-staging remap: R7's wave-owns-k-pair put (w&3) -- wave-fixed -- in
//     bank bits 1:0 and j-fixed parity in bit 4 => 4 reachable banks =
//     16-way conflict (~2us of LDS-pipe time). New map: lane owns k-pair
//     (b_kp = tid&15) and n-quad (b_i = tid>>4); bank = 16(j&1) +
//     4*((kp>>2)^g2x(row)) + (kp&3): kp spans 16 values per instr -> 16
//     banks -> 4-way (the b32 structural floor). Cost: B global runs drop
//     128B -> 64B (still sector-aligned; +256 requests/phase << delivery).
// (2) B ring-3 prefetch: L_B(t+1) AND L_B(t+2) outstanding during phase t,
//     so the memory pipe stays fed across the stage/compute/barrier tail
//     (R7 idles ~25% of each phase once L(t+1) lands). +8 VGPR.
//
// B swizzle g2x(n) = ((n>>1) ^ (n>>3)) & 3:
//   element (n,k) at byte n*64 + (((k>>3) ^ g2x(n))<<4) + (2k mod 16).
//   Reads (bf16x8, 16 consecutive n, fixed c16): (n&1, g2x(n)) covers all
//   8 combos in any 8 consecutive n -> 8 distinct b128 start-banks x 4 banks
//   = 32 banks / 16 lanes = 2/bank = FREE (m136).
__device__ __forceinline__ int g2x(int n) { return ((n >> 1) ^ (n >> 3)) & 3; }

__global__ __launch_bounds__(1024, 4)
void gld_mfma_kernel(const float* __restrict__ code,
                     const float* __restrict__ W,
                     float* __restrict__ out)
{
    const int tid = threadIdx.x;

    // XCD swizzle: id = ll + 8*(n_idx + 4*lh), l = 8*lh + ll. The 4 n-blocks
    // of filter l share id%8 -> same XCD; they share the code[:,l,:] panel
    // (the 4x-amplified operand) so re-reads are XCD-L2 hits.
    const int id   = blockIdx.x;
    const int ll   = id & 7;
    const int rest = id >> 3;                // 0..31
    const int n0   = (rest & 3) * 256;       // HW cols (4 slices of 256)
    const int l    = (rest >> 2) * 8 + ll;   // filter

    __shared__ unsigned char Alds[2][256 * LDA_ROW];  // ping-pong A tiles (2 x 20 KB)
    __shared__ unsigned char Blds[2][256 * LDB_ROW];  // ping-pong B tiles (2 x 16 KB)

    const int lane = tid & 63;
    const int wave = tid >> 6;          // 0..15
    const int wm = (wave >> 2) * 64;    // m offset of wave (4 m-waves)
    const int wn = (wave & 3) * 64;     // n offset of wave (4 n-waves)

    floatx4 acc[4][4];
    #pragma unroll
    for (int i = 0; i < 4; ++i)
        #pragma unroll
        for (int j = 0; j < 4; ++j)
            acc[i][j] = (floatx4)0.0f;

    // A staging (R7-verified): 256 rows x 32 k fp32 = 2 float4/thread.
    // a_row = tid>>2 (0..255), k = 4*(tid&3) and +16. Per instr: 16 rows x
    // 64 B contiguous runs; instr pair covers full 128-B lines.
    const int a_row = tid >> 2;
    const int a_k4  = (tid & 3) * 4;
    // B staging (NEW map): thread owns n-quad x k-pair micro-tile.
    //   b_kp = tid & 15: k-pair (k = 2*b_kp, 2*b_kp+1 within the 32-k tile)
    //   b_i  = tid >> 4: n-quad (n = 4*b_i + j)
    // Per instr: 16 k-rows, each covered by 4 lanes x 16 B = 64-B runs.
    const int b_kp = tid & 15;
    const int b_i  = tid >> 4;

    const float* aBase = code + (size_t)l * C_ + a_k4;
    const float* wBase = W + (size_t)l * (C_ * HW_) + (size_t)(2 * b_kp) * HW_ + n0 + 4 * b_i;

    floatx4 Areg[2][2];   // A set s holds tile t with s = t&1 (1-phase slack)
    floatx4 Breg[3][2];   // B ring-3: slot t%3 holds tile t (2-phase slack)

    // ---- prologue: A(0), B(0), B(1) ----
    Areg[0][0] = *(const floatx4*)(aBase + (size_t)a_row * (L_ * C_));
    Areg[0][1] = *(const floatx4*)(aBase + (size_t)a_row * (L_ * C_) + 16);
    #pragma unroll
    for (int r = 0; r < 2; ++r)
        Breg[0][r] = *(const floatx4*)(wBase + (size_t)r * HW_);
    #pragma unroll
    for (int r = 0; r < 2; ++r)
        Breg[1][r] = *(const floatx4*)(wBase + (size_t)(32 + r) * HW_);

    // B LDS write addresses (loop-invariant): row 4*b_i+j, k-pair b_kp at
    // byte row*64 + (((b_kp>>2) ^ g2x(row))<<4) + ((b_kp&3)<<2)
    int bwaddr[4];
    #pragma unroll
    for (int j = 0; j < 4; ++j) {
        const int row = 4 * b_i + j;
        bwaddr[j] = row * LDB_ROW + ((((b_kp >> 2) ^ g2x(row))) << 4) + ((b_kp & 3) << 2);
    }
    // A LDS write byte: row*80 + 2*a_k4 (and +32 for the k+16 half)
    const int awaddr = a_row * LDA_ROW + 2 * a_k4;

    // ---- pipelined main loop: 8 phases (BK=32) + compute tail ----
    #pragma unroll
    for (int t = 0; t < 8; ++t) {               // fully unrolled: all indices static
        const int sb = t & 1;
        const int kb = t * 32;

        // (1) issue A(t+1) -- 1 phase of slack covers its latency.
        if (t < 7) {
            Areg[sb ^ 1][0] = *(const floatx4*)(aBase + (size_t)a_row * (L_ * C_) + (kb + 32));
            Areg[sb ^ 1][1] = *(const floatx4*)(aBase + (size_t)a_row * (L_ * C_) + (kb + 48));
        }
        // (2) issue B(t+2) into ring slot (t+2)%3 -- keeps 2 B-tiles in
        //     flight so the memory pipe stays busy through the phase tail.
        if (t < 6) {
            #pragma unroll
            for (int r = 0; r < 2; ++r)
                Breg[(t + 2) % 3][r] = *(const floatx4*)(wBase + (size_t)(kb + 64 + r) * HW_);
        }

        // (3) compute tile t-1 from the OTHER buffer -- independent of this
        //     phase's in-flight loads; MFMA proceeds while L(t) drains.
        if (t > 0) {
            const unsigned char* Ab = Alds[sb ^ 1];
            const unsigned char* Bb = Blds[sb ^ 1];
            bf16x8 af[4], bfr[4];
            const int c16 = lane >> 4;                    // k-chunk 0..3
            #pragma unroll
            for (int i = 0; i < 4; ++i)
                af[i] = *(const bf16x8*)&Ab[(wm + i * 16 + (lane & 15)) * LDA_ROW + c16 * 16];
            #pragma unroll
            for (int j = 0; j < 4; ++j) {
                const int n = wn + j * 16 + (lane & 15);
                bfr[j] = *(const bf16x8*)&Bb[n * LDB_ROW + ((c16 ^ g2x(n)) << 4)];
            }
            #pragma unroll
            for (int i = 0; i < 4; ++i)
                #pragma unroll
                for (int j = 0; j < 4; ++j)
                    acc[i][j] = __builtin_amdgcn_mfma_f32_16x16x32_bf16(af[i], bfr[j], acc[i][j], 0, 0, 0);
        }

        // (4) stage B(t) first (arrived 2 phases ago -> no vmcnt stall),
        //     then A(t) (1-phase slack; compiler-counted wait leaves the
        //     younger A(t+1)/B(t+1)/B(t+2) loads outstanding).
        {
            const int r3 = t % 3;
            #pragma unroll
            for (int j = 0; j < 4; ++j) {
                bf16x2 h;
                h.x = (__bf16)Breg[r3][0][j];    // k = 2*b_kp
                h.y = (__bf16)Breg[r3][1][j];    // k = 2*b_kp + 1
                *(bf16x2*)&Blds[sb][bwaddr[j]] = h;
            }
        }
        #pragma unroll
        for (int p = 0; p < 2; ++p) {
            bf16x4 h;
            h.x = (__bf16)Areg[sb][p].x; h.y = (__bf16)Areg[sb][p].y;
            h.z = (__bf16)Areg[sb][p].z; h.w = (__bf16)Areg[sb][p].w;
            *(bf16x4*)&Alds[sb][awaddr + p * 32] = h;
        }

        // (5) ONE barrier per phase.
        BARRIER_LDS();
    }

    // ---- tail: compute tile 7 (staged in phase 7 into buf 1) ----
    {
        const unsigned char* Ab = Alds[1];
        const unsigned char* Bb = Blds[1];
        bf16x8 af[4], bfr[4];
        const int c16 = lane >> 4;
        #pragma unroll
        for (int i = 0; i < 4; ++i)
            af[i] = *(const bf16x8*)&Ab[(wm + i * 16 + (lane & 15)) * LDA_ROW + c16 * 16];
        #pragma unroll
        for (int j = 0; j < 4; ++j) {
            const int n = wn + j * 16 + (lane & 15);
            bfr[j] = *(const bf16x8*)&Bb[n * LDB_ROW + ((c16 ^ g2x(n)) << 4)];
        }
        #pragma unroll
        for (int i = 0; i < 4; ++i)
            #pragma unroll
            for (int j = 0; j < 4; ++j)
                acc[i][j] = __builtin_amdgcn_mfma_f32_16x16x32_bf16(af[i], bfr[j], acc[i][j], 0, 0, 0);
    }

    // ---- epilogue: C/D layout col=lane&15, row=(lane>>4)*4+reg ----
    const int col0 = lane & 15;
    const int row0 = (lane >> 4) * 4;
    #pragma unroll
    for (int i = 0; i < 4; ++i) {
        #pragma unroll
        for (int j = 0; j < 4; ++j) {
            const int m = wm + i * 16 + row0;              // BM = whole batch
            const int n = n0 + wn + j * 16 + col0;
            float* o = out + (size_t)m * (L_ * HW_) + (size_t)l * HW_ + n;
            #pragma unroll
            for (int r = 0; r < 4; ++r)
                o[(size_t)r * (L_ * HW_)] = acc[i][j][r];
        }
    }
}

extern "C" void kernel_launch(void* const* d_in, const int* in_sizes, int n_in,
                              void* d_out, int out_size, void* d_ws, size_t ws_size,
                              hipStream_t stream) {
    const float* code = (const float*)d_in[0];   // [256, 64, 256] fp32
    const float* W    = (const float*)d_in[1];   // [64, 256, 1024] fp32
    float* out        = (float*)d_out;           // [256, 64, 32, 32] fp32

    gld_mfma_kernel<<<dim3(256), 1024, 0, stream>>>(code, W, out);
}